// Round 12
// baseline (113.850 us; speedup 1.0000x reference)
//
#include <hip/hip_runtime.h>

typedef __bf16 bf16x8 __attribute__((ext_vector_type(8)));
typedef float f32x4 __attribute__((ext_vector_type(4)));
typedef unsigned short u16x8 __attribute__((ext_vector_type(8)));

#define MFMA16(a, b, c) __builtin_amdgcn_mfma_f32_16x16x32_bf16((a), (b), (c), 0, 0, 0)

#define INVPI 0.31830988618379067f
#define TBL_N 4096
#define TBL_SCALE 409.6f          // TBL_N / gamma_range(10)
#define TBL_STEP (10.f / 4096.f)

__device__ __forceinline__ unsigned short f2bf(float f) {
    unsigned int u = __float_as_uint(f);
    u = u + 0x7FFFu + ((u >> 16) & 1u);   // round-to-nearest-even
    return (unsigned short)(u >> 16);
}

// f(y) = -y + sin^2(y+gamma) = 0.5 - 0.5*cos(2y+2gamma) - y
__device__ __forceinline__ float feval(float y, float gp) {
    float u = fmaf(y, INVPI, gp);
    float cc = __builtin_amdgcn_cosf(u);
    return fmaf(-0.5f, cc, 0.5f - y);
}

// ---------------- K0: prep — weight converts + ODE table ----------------
// blocks   0..127 : w2 -> bf16 (8 elem/thread)
// blocks 128..143 : w3 yt-part -> bf16
// blocks 144..159 : 4096-entry ODE table
__global__ void k_prep(const float* __restrict__ w2W, const float* __restrict__ w3W,
                       const float* __restrict__ wp,
                       unsigned short* __restrict__ w2bf, unsigned short* __restrict__ w3bbf,
                       float* __restrict__ tbl) {
    int blk = blockIdx.x;
    if (blk < 128) {
        int i = (blk * 256 + threadIdx.x) * 8;
        const float4* s4 = reinterpret_cast<const float4*>(w2W + i);
        float4 a = s4[0], b = s4[1];
        u16x8 o;
        o[0] = f2bf(a.x); o[1] = f2bf(a.y); o[2] = f2bf(a.z); o[3] = f2bf(a.w);
        o[4] = f2bf(b.x); o[5] = f2bf(b.y); o[6] = f2bf(b.z); o[7] = f2bf(b.w);
        *reinterpret_cast<u16x8*>(w2bf + i) = o;
        return;
    }
    if (blk < 144) {
        int idx = ((blk - 128) * 256 + threadIdx.x) * 8;   // < 32768
        int j = idx >> 8, dk = idx & 255;
        const float4* s4 = reinterpret_cast<const float4*>(w3W + j * 1280 + 1024 + dk);
        float4 a = s4[0], b = s4[1];
        u16x8 o;
        o[0] = f2bf(a.x); o[1] = f2bf(a.y); o[2] = f2bf(a.z); o[3] = f2bf(a.w);
        o[4] = f2bf(b.x); o[5] = f2bf(b.y); o[6] = f2bf(b.z); o[7] = f2bf(b.w);
        *reinterpret_cast<u16x8*>(w3bbf + idx) = o;
        return;
    }
    {
        int gid = (blk - 144) * 256 + threadIdx.x;   // 0..4095

        float c[21];
#pragma unroll
        for (int g = 0; g < 21; ++g) c[g] = 0.f;
        {
            float wv[10];
#pragma unroll
            for (int t = 0; t < 10; ++t) wv[t] = wp[t];
            float m = wv[0];
#pragma unroll
            for (int t = 1; t < 10; ++t) m = fmaxf(m, wv[t]);
            float s = 0.f;
#pragma unroll
            for (int t = 0; t < 10; ++t) { wv[t] = __expf(wv[t] - m); s += wv[t]; }
            float inv = 1.f / s;
            const int   idxs[10]  = {0, 2, 4, 6, 8, 11, 13, 15, 17, 19};
            const float fracs[10] = {0.f, 0.22222222f, 0.44444445f, 0.6666667f, 0.8888889f,
                                     0.11111111f, 0.33333334f, 0.5555556f, 0.7777778f, 1.0f};
#pragma unroll
            for (int t = 0; t < 10; ++t) {
                float w = wv[t] * inv;
                c[idxs[t]]     += w * (1.f - fracs[t]);
                c[idxs[t] + 1] += w * fracs[t];
            }
        }

        float gamma = gid * TBL_STEP;
        float gp = gamma * INVPI;
        float y = 0.f, acc = 0.f;
#pragma unroll
        for (int st = 0; st < 20; ++st) {
            float k1 = feval(y, gp);
            float k2 = feval(fmaf(0.05f, k1, y), gp);
            float k3 = feval(fmaf(0.05f, k2, y), gp);
            float k4 = feval(fmaf(0.1f,  k3, y), gp);
            float sm = k1 + k4;
            sm = fmaf(2.f, k2, sm);
            sm = fmaf(2.f, k3, sm);
            y  = fmaf(0.1f / 6.0f, sm, y);
            acc = fmaf(c[st + 1], y, acc);
        }
        tbl[gid] = acc;
    }
}

// ---------------- K1: feature = relu(x@w1^T+b1) ; yt = lerp(tbl, feature) ----------------
// R4-proven (VGPR 32, no spill). 3200 blocks x 256 threads, 8 elem/thread.
__global__ void __launch_bounds__(256) k_feat(
    const float* __restrict__ x, const float* __restrict__ w1W, const float* __restrict__ w1b,
    const float* __restrict__ tbl,
    unsigned short* __restrict__ featbf, unsigned short* __restrict__ ytbf) {

    __shared__ float tl[TBL_N];
    {
        const float4* g4 = reinterpret_cast<const float4*>(tbl);
        float4* l4 = reinterpret_cast<float4*>(tl);
#pragma unroll
        for (int r = 0; r < 4; ++r) l4[r * 256 + threadIdx.x] = g4[r * 256 + threadIdx.x];
    }
    __syncthreads();

    int tid  = blockIdx.x * 256 + threadIdx.x;    // 819,200 threads
    int base = tid * 8;
    int row  = base >> 8;        // 0..25599
    int d0   = base & 255;       // multiple of 8

    float x0 = x[row * 3 + 0], x1 = x[row * 3 + 1], x2v = x[row * 3 + 2];

    float wreg[24];
    {
        const float4* w4 = reinterpret_cast<const float4*>(w1W + d0 * 3);
#pragma unroll
        for (int q = 0; q < 6; ++q) *reinterpret_cast<float4*>(&wreg[q * 4]) = w4[q];
    }
    float bb[8];
    {
        const float4* b4 = reinterpret_cast<const float4*>(w1b + d0);
        *reinterpret_cast<float4*>(&bb[0]) = b4[0];
        *reinterpret_cast<float4*>(&bb[4]) = b4[1];
    }

    u16x8 fbv, ybv;
#pragma unroll
    for (int j = 0; j < 8; ++j) {
        float g = fmaf(x0, wreg[j * 3], fmaf(x1, wreg[j * 3 + 1], fmaf(x2v, wreg[j * 3 + 2], bb[j])));
        g = fmaxf(g, 0.f);
        fbv[j] = f2bf(g);
        float t = g * TBL_SCALE;
        int i = (int)t;
        i = (i > TBL_N - 2) ? (TBL_N - 2) : i;
        float fr = t - (float)i;
        float a = tl[i], b = tl[i + 1];
        ybv[j] = f2bf(fmaf(fr, b - a, a));
    }
    *reinterpret_cast<u16x8*>(featbf + base) = fbv;
    *reinterpret_cast<u16x8*>(ytbf + base) = ybv;
}

// ---------------- K_G: GEMM2 + relu + max + v (one block per batch) ----------------
// 256 blocks x 256 threads (4 waves). LDS 61.4 KB.
// Stage feature[b] ONCE (global_load_lds, inverse-swizzled source, linear dest);
// loop 4 col-quarters with R4's proven acc[7][4] MFMA body; then
// vglob[b][j] = xs[0..1023] . w3W[j,0..1023] + w3b[j]  (shfl-reduce, coalesced).
__global__ void __launch_bounds__(256, 2) k_G(
    const unsigned short* __restrict__ featbf, const unsigned short* __restrict__ w2bf,
    const float* __restrict__ w2b, const float* __restrict__ w3W,
    const float* __restrict__ w3b, float* __restrict__ vglob) {

    __shared__ __align__(1024) char smemA[57344];   // feature, 112 rows x 512 B
    __shared__ float xs[1024];                      // col-max of x2

    const int b = blockIdx.x;
    const int wave = threadIdx.x >> 6, lane = threadIdx.x & 63;
    const int col16 = lane & 15, krow = lane >> 4;
    const int sw = (col16 & 7) << 4;

    // ---- stage A once: pairs of rows (1 KB each); wave w owns pairs {w, w+4,...} ----
    {
        const unsigned short* src = featbf + (size_t)b * 25600;
        int r_in_pair = lane >> 5;           // 0..1
        int chp = lane & 31;                 // linear 16B chunk in row
#pragma unroll
        for (int k = 0; k < 14; ++k) {
            int pr = wave + k * 4;           // pair index 0..55
            int row = pr * 2 + r_in_pair;
            if (pr < 50) {
                int ch = chp ^ (row & 7);
                const unsigned short* g = src + row * 256 + ch * 8;
                __builtin_amdgcn_global_load_lds(
                    (const __attribute__((address_space(1))) void*)g,
                    (__attribute__((address_space(3))) void*)(smemA + pr * 1024),
                    16, 0, 0);
            } else {
                // rows 100..111: zero padding
                *reinterpret_cast<f32x4*>(smemA + pr * 1024 + lane * 16) = (f32x4){0.f,0.f,0.f,0.f};
            }
        }
    }
    __syncthreads();

    // ---- P2: 4 quarters x (wave owns 64 cols): GEMM + relu + col-max ----
#pragma unroll 1
    for (int q = 0; q < 4; ++q) {
        int colbase = q * 256 + wave * 64;
        const unsigned short* bp = w2bf + (size_t)(colbase + col16) * 256 + krow * 8;

        f32x4 acc[7][4];
#pragma unroll
        for (int mt = 0; mt < 7; ++mt)
#pragma unroll
            for (int ct = 0; ct < 4; ++ct) acc[mt][ct] = (f32x4){0.f, 0.f, 0.f, 0.f};

        bf16x8 Bcur[4], Bnxt[4];
#pragma unroll
        for (int ct = 0; ct < 4; ++ct)
            Bcur[ct] = *reinterpret_cast<const bf16x8*>(bp + ct * 4096);

#pragma unroll
        for (int k0 = 0; k0 < 8; ++k0) {
            int off = (k0 * 64 + krow * 16) ^ sw;
            if (k0 < 7) {
#pragma unroll
                for (int ct = 0; ct < 4; ++ct)
                    Bnxt[ct] = *reinterpret_cast<const bf16x8*>(bp + ct * 4096 + (k0 + 1) * 32);
            }
#pragma unroll
            for (int mt = 0; mt < 7; ++mt) {
                bf16x8 Af = *reinterpret_cast<const bf16x8*>(smemA + (mt * 16 + col16) * 512 + off);
#pragma unroll
                for (int ct = 0; ct < 4; ++ct)
                    acc[mt][ct] = MFMA16(Af, Bcur[ct], acc[mt][ct]);
            }
#pragma unroll
            for (int ct = 0; ct < 4; ++ct) Bcur[ct] = Bnxt[ct];
        }

        float bias[4], m[4];
#pragma unroll
        for (int ct = 0; ct < 4; ++ct) {
            bias[ct] = w2b[colbase + ct * 16 + col16];
            m[ct] = 0.f;   // true max >= 0 (relu, 100 valid rows)
        }
#pragma unroll
        for (int mt = 0; mt < 7; ++mt) {
#pragma unroll
            for (int r = 0; r < 4; ++r) {
                bool valid = (mt * 16 + krow * 4 + r) < 100;
#pragma unroll
                for (int ct = 0; ct < 4; ++ct) {
                    float v = fmaxf(acc[mt][ct][r] + bias[ct], 0.f);
                    if (valid) m[ct] = fmaxf(m[ct], v);
                }
            }
        }
#pragma unroll
        for (int ct = 0; ct < 4; ++ct) {
            m[ct] = fmaxf(m[ct], __shfl_xor(m[ct], 16));
            m[ct] = fmaxf(m[ct], __shfl_xor(m[ct], 32));
        }
        if (lane < 16) {
#pragma unroll
            for (int ct = 0; ct < 4; ++ct)
                xs[colbase + ct * 16 + lane] = m[ct];
        }
    }
    __syncthreads();

    // ---- P3: vglob[b][j] = sum_c xs[c]*w3W[j][c] + w3b[j] (wave handles 32 j) ----
    {
        int j = wave * 32;
#pragma unroll 2
        for (int jj = 0; jj < 32; ++jj, ++j) {
            const float* wr = w3W + (size_t)j * 1280;
            float s = 0.f;
#pragma unroll
            for (int cc = 0; cc < 16; ++cc) {
                int c = cc * 64 + lane;
                s = fmaf(xs[c], wr[c], s);
            }
            s += __shfl_xor(s, 1);  s += __shfl_xor(s, 2);  s += __shfl_xor(s, 4);
            s += __shfl_xor(s, 8);  s += __shfl_xor(s, 16); s += __shfl_xor(s, 32);
            if (lane == 0) vglob[(size_t)b * 128 + j] = s + w3b[j];
        }
    }
}

// ---------------- K_B: h3 = relu(v + yt @ w3b^T) ; out = h3 @ outW^T + outb ----------------
// grid 800: 32 rows per block; 4 waves, wave owns 32 cols (2 n-tiles)
__global__ void __launch_bounds__(256) k_B(
    const unsigned short* __restrict__ ytbf, const unsigned short* __restrict__ w3bbf,
    const float* __restrict__ vglob, const float* __restrict__ outW,
    const float* __restrict__ outb, float* __restrict__ out) {

    __shared__ float h3s[32][132];
    int rbase = blockIdx.x * 32;
    int wave = threadIdx.x >> 6, lane = threadIdx.x & 63;
    int col16 = lane & 15, krow = lane >> 4;

    const unsigned short* ap0 = ytbf + (size_t)(rbase + col16) * 256 + krow * 8;
    const unsigned short* ap1 = ap0 + 16 * 256;
    const unsigned short* bp0 = w3bbf + (size_t)(wave * 32 + col16) * 256 + krow * 8;
    const unsigned short* bp1 = bp0 + 16 * 256;

    f32x4 a00 = {0.f,0.f,0.f,0.f}, a01 = {0.f,0.f,0.f,0.f};
    f32x4 a10 = {0.f,0.f,0.f,0.f}, a11 = {0.f,0.f,0.f,0.f};
#pragma unroll
    for (int k0 = 0; k0 < 8; ++k0) {
        bf16x8 A0 = *reinterpret_cast<const bf16x8*>(ap0 + k0 * 32);
        bf16x8 A1 = *reinterpret_cast<const bf16x8*>(ap1 + k0 * 32);
        bf16x8 B0 = *reinterpret_cast<const bf16x8*>(bp0 + k0 * 32);
        bf16x8 B1 = *reinterpret_cast<const bf16x8*>(bp1 + k0 * 32);
        a00 = MFMA16(A0, B0, a00);
        a01 = MFMA16(A0, B1, a01);
        a10 = MFMA16(A1, B0, a10);
        a11 = MFMA16(A1, B1, a11);
    }

#pragma unroll
    for (int mt = 0; mt < 2; ++mt) {
#pragma unroll
        for (int nt = 0; nt < 2; ++nt) {
            f32x4 acc = (mt == 0) ? ((nt == 0) ? a00 : a01) : ((nt == 0) ? a10 : a11);
#pragma unroll
            for (int r = 0; r < 4; ++r) {
                int rloc  = mt * 16 + krow * 4 + r;
                int rglob = rbase + rloc;
                int bb    = rglob / 100;
                int col   = wave * 32 + nt * 16 + col16;
                float h = acc[r] + vglob[(size_t)bb * 128 + col];
                h3s[rloc][col] = fmaxf(h, 0.f);
            }
        }
    }
    __syncthreads();

    int r  = threadIdx.x >> 3;   // 0..31
    int jg = threadIdx.x & 7;    // 0..7
    float p0 = 0.f, p1 = 0.f;
#pragma unroll
    for (int tt = 0; tt < 16; ++tt) {
        int j = jg * 16 + tt;
        float h = h3s[r][j];
        p0 = fmaf(h, outW[j], p0);
        p1 = fmaf(h, outW[128 + j], p1);
    }
    p0 += __shfl_xor(p0, 1); p0 += __shfl_xor(p0, 2); p0 += __shfl_xor(p0, 4);
    p1 += __shfl_xor(p1, 1); p1 += __shfl_xor(p1, 2); p1 += __shfl_xor(p1, 4);
    if (jg == 0) {
        int rg = rbase + r;
        out[rg * 2 + 0] = p0 + outb[0];
        out[rg * 2 + 1] = p1 + outb[1];
    }
}

extern "C" void kernel_launch(void* const* d_in, const int* in_sizes, int n_in,
                              void* d_out, int out_size, void* d_ws, size_t ws_size,
                              hipStream_t stream) {
    const float* x    = (const float*)d_in[0];
    const float* w1W  = (const float*)d_in[1];
    const float* w1b  = (const float*)d_in[2];
    const float* w2W  = (const float*)d_in[3];
    const float* w2b  = (const float*)d_in[4];
    const float* w3W  = (const float*)d_in[5];
    const float* w3b  = (const float*)d_in[6];
    const float* outW = (const float*)d_in[7];
    const float* outb = (const float*)d_in[8];
    const float* wp   = (const float*)d_in[9];
    float* out = (float*)d_out;

    char* ws = (char*)d_ws;
    unsigned short* featbf = (unsigned short*)(ws);                 // 13,107,200 B
    unsigned short* ytbf   = (unsigned short*)(ws + 13107200);      // 13,107,200 B
    unsigned short* w2bf_  = (unsigned short*)(ws + 26214400);      // 524,288 B
    unsigned short* w3bbf_ = (unsigned short*)(ws + 26738688);      // 65,536 B
    float* tbl             = (float*)(ws + 26804224);               // 16,384 B
    float* vglob           = (float*)(ws + 26820608);               // 131,072 B
    // total ws use: 26,951,680 B

    k_prep<<<160, 256, 0, stream>>>(w2W, w3W, wp, w2bf_, w3bbf_, tbl);
    k_feat<<<3200, 256, 0, stream>>>(x, w1W, w1b, tbl, featbf, ytbf);
    k_G<<<256, 256, 0, stream>>>(featbf, w2bf_, w2b, w3W, w3b, vglob);
    k_B<<<800, 256, 0, stream>>>(ytbf, w3bbf_, vglob, outW, outb, out);
}